// Round 12
// baseline (17961.998 us; speedup 1.0000x reference)
//
#include <hip/hip_runtime.h>
#include <hip/hip_bf16.h>
#include <cstdint>
#include <cstddef>

using f16 = _Float16;
typedef _Float16 f16x2 __attribute__((ext_vector_type(2)));
typedef _Float16 f16x8v __attribute__((ext_vector_type(8)));
typedef float f32x4v __attribute__((ext_vector_type(4)));

static constexpr int DD = 31;                      // depth (time) extent
static constexpr long long U  = 31LL * 256 * 256;  // elems of one channel @256
static constexpr long long V2 = 31LL * 128 * 128;
static constexpr long long V3 = 31LL * 64 * 64;
static constexpr long long POOL_UNITS = 56;        // pool = 56*U f16 (~227MB)
static constexpr int CP_CHUNK = 16;                // dot2 path LDS chunk (pairs)

union U32H2 { unsigned u; f16x2 h; };
union ABFrag { uint4 u; f16x8v h; f16 e[8]; };

__device__ __forceinline__ float toF(float v) { return v; }
__device__ __forceinline__ float toF(f16 v) { return (float)v; }
__device__ __forceinline__ void stv(float* p, float v) { *p = v; }
__device__ __forceinline__ void stv(f16* p, float v) { *p = (f16)v; }
__device__ __forceinline__ float sigm(float x) { return 1.f / (1.f + __expf(-x)); }

__device__ __forceinline__ unsigned packh2(float a, float b)
{
    U32H2 r; r.h = f16x2{(f16)a, (f16)b}; return r.u;
}
__device__ __forceinline__ unsigned addh2(unsigned a, unsigned b)
{
    U32H2 x, y, r; x.u = a; y.u = b; r.h = x.h + y.h; return r.u;
}
__device__ __forceinline__ float dot2f(unsigned v, unsigned w, float c)
{
#if __has_builtin(__builtin_amdgcn_fdot2)
    U32H2 uv, uw; uv.u = v; uw.u = w;
    return __builtin_amdgcn_fdot2(uv.h, uw.h, c, false);
#else
    U32H2 uv, uw; uv.u = v; uw.u = w;
    c = fmaf((float)uv.h.x, (float)uw.h.x, c);
    return fmaf((float)uv.h.y, (float)uw.h.y, c);
#endif
}

// ---------------------------------------------------------------------------
__global__ __launch_bounds__(256)
void fill_k(f16* p, long long n)
{
    const long long stride = (long long)gridDim.x * 256;
    for (long long i = (long long)blockIdx.x * 256 + threadIdx.x; i < n; i += stride)
        p[i] = (f16)0.f;
}

// ---------------------------------------------------------------------------
// MFMA implicit-GEMM conv3d, 3x3x3, pad 1, pair-interleaved f16 tensors
// [C/2][D][H][W][2]. Wave tile: M=16 consecutive w x N=16 co; block = 4 waves
// = 64 consecutive w of one (d,h) row. K = ci, chunks of 32 (zero-padded if
// Cin<32 in a chunk). v_mfma_f32_16x16x32_f16 fragments:
//   A[m=lane&15][k=(lane>>4)*8+j]   (8 f16 = 4 IL2 dwords, adjacent-K pairs)
//   B[k=(lane>>4)*8+j][n=lane&15]   (prepacked per-tap in LDS, 1 ds_read_b128)
//   D[m=(lane>>4)*4+reg][n=lane&15]
// UP: input = upsample2x(inA + inB) with Hin/Win = LO-res dims.
// co is chunk-relative; weights guarded by CoRem; store first nStore of 16.
// Requires Wout % 64 == 0.
// ---------------------------------------------------------------------------
template<int STRIDE, bool FLIP, bool UP>
__global__ __launch_bounds__(256)
void conv_mfma_k(const f16* __restrict__ inA, const f16* __restrict__ inB,
                 const float* __restrict__ wt, const float* __restrict__ bias,
                 f16* __restrict__ out, int Cin, int CoRem, int nStore,
                 int Hin, int Win, int Hout, int Wout)
{
    __shared__ uint4 lb[27 * 64];
    const int lane = threadIdx.x & 63;
    const int wid = threadIdx.x >> 6;
    const int quad = lane >> 4;
    const int r = lane & 15;

    const int wsegs = Wout >> 6;
    int t = blockIdx.x;
    const int ws = t % wsegs; t /= wsegs;
    const int h0 = t % Hout;
    const int d0 = t / Hout;
    const int w0 = ws * 64 + wid * 16;

    const int co = blockIdx.y * 16 + r;   // chunk-relative out channel (n)
    const float bv = (co < CoRem) ? bias[co] : 0.f;
    f32x4v acc = { bv, bv, bv, bv };

    const size_t HWin = (size_t)Hin * Win;       // lo-res plane for UP
    const size_t cpStride = (size_t)DD * HWin;   // dwords between cp planes
    const unsigned* iu = (const unsigned*)inA;
    const unsigned* iub = (const unsigned*)inB;

    for (int ci0 = 0; ci0 < Cin; ci0 += 32) {
        // ---- stage B fragments for all 27 taps ----
        __syncthreads();
        for (int i = threadIdx.x; i < 27 * 64; i += 256) {
            const int l = i & 63;
            const int tap = i >> 6;
            const int q = l >> 4;
            const int rr = l & 15;
            int src;
            if (FLIP) {
                const int kd = tap / 9, kh = (tap / 3) % 3, kw = tap % 3;
                src = (2 - kd) * 9 + (2 - kh) * 3 + (2 - kw);
            } else {
                src = tap;
            }
            const int cc = blockIdx.y * 16 + rr;
            const bool cv = (cc < CoRem);
            ABFrag v;
#pragma unroll
            for (int j = 0; j < 8; ++j) {
                const int ci = ci0 + q * 8 + j;
                v.e[j] = (cv && ci < Cin)
                         ? (f16)wt[((size_t)cc * Cin + ci) * 27 + src] : (f16)0.f;
            }
            lb[i] = v.u;
        }
        __syncthreads();

        const int cpB = (ci0 >> 1) + quad * 4;          // lane's first cp
        const bool cok = (ci0 + quad * 8) < Cin;        // quad K-slice valid

        for (int kd = 0; kd < 3; ++kd) {
            const int di = d0 + kd - 1;
            if (di < 0 || di >= DD) continue;
            for (int kh = 0; kh < 3; ++kh) {
                const int hlim = UP ? (2 * Hin) : Hin;
                const int hi = UP ? (h0 + kh - 1) : (h0 * STRIDE + kh - 1);
                if (hi < 0 || hi >= hlim) continue;
                const int hr = UP ? (hi >> 1) : hi;
                const size_t rowOff = (size_t)di * HWin + (size_t)hr * Win;
#pragma unroll
                for (int kw = 0; kw < 3; ++kw) {
                    int wi, wlim;
                    if (UP)              { wi = w0 + r + kw - 1;        wlim = 2 * Win; }
                    else if (STRIDE == 1){ wi = w0 + r + kw - 1;        wlim = Win; }
                    else                 { wi = 2 * (w0 + r) + kw - 1;  wlim = Win; }
                    const bool ok = (wi >= 0) && (wi < wlim) && cok;
                    int wr = UP ? (wi >> 1) : wi;
                    wr = wr < 0 ? 0 : (wr > Win - 1 ? Win - 1 : wr);
                    unsigned dv[4];
#pragma unroll
                    for (int c = 0; c < 4; ++c) {
                        const size_t off = (size_t)(cpB + c) * cpStride + rowOff + wr;
                        unsigned va = iu[off];
                        if (UP) va = addh2(va, iub[off]);
                        dv[c] = ok ? va : 0u;
                    }
                    ABFrag a; a.u = make_uint4(dv[0], dv[1], dv[2], dv[3]);
                    ABFrag b; b.u = lb[(kd * 9 + kh * 3 + kw) * 64 + lane];
                    acc = __builtin_amdgcn_mfma_f32_16x16x32_f16(a.h, b.h, acc, 0, 0, 0);
                }
            }
        }
    }

    if (r < nStore) {
        const size_t base = ((((size_t)(co >> 1) * DD + d0) * Hout + h0)
                             * (size_t)Wout) * 2 + (co & 1);
#pragma unroll
        for (int reg = 0; reg < 4; ++reg) {
            const int w = w0 + quad * 4 + reg;
            out[base + (size_t)w * 2] = (f16)acc[reg];
        }
    }
}

// ---------------------------------------------------------------------------
// Legacy dot2 conv (kept for the rec layer: nCo=3, plain f16 output).
// ---------------------------------------------------------------------------
template<int STRIDE, bool FLIP, int CO_BLK, bool OUT_IL>
__global__ __launch_bounds__(256)
void conv3d_il_k(const f16* __restrict__ in, const float* __restrict__ wt,
                 const float* __restrict__ bias, f16* __restrict__ out,
                 int Cin, int Hin, int Win, int Hout, int Wout)
{
    extern __shared__ unsigned wl2[];
    const int co_base = blockIdx.y * CO_BLK;
    const int s8 = (blockIdx.x * 256 + threadIdx.x) * 8;
    const int w0 = s8 % Wout;
    const int sh = s8 / Wout;
    const int h0 = sh % Hout;
    const int d0 = sh / Hout;

    float acc[CO_BLK][8];
#pragma unroll
    for (int j = 0; j < CO_BLK; ++j) {
        const float bvv = bias[co_base + j];
#pragma unroll
        for (int o = 0; o < 8; ++o) acc[j][o] = bvv;
    }
    const size_t HWin = (size_t)Hin * Win;
    const int CP = Cin >> 1;

    for (int cp0 = 0; cp0 < CP; cp0 += CP_CHUNK) {
        const int cnp = (CP - cp0 < CP_CHUNK) ? (CP - cp0) : CP_CHUNK;
        __syncthreads();
        for (int t = threadIdx.x; t < cnp * 27 * CO_BLK; t += 256) {
            const int j = t % CO_BLK;
            const int k = (t / CO_BLK) % 27;
            const int cp = t / (CO_BLK * 27);
            int src;
            if (FLIP) {
                const int kd = k / 9, kh = (k / 3) % 3, kw = k % 3;
                src = (2 - kd) * 9 + (2 - kh) * 3 + (2 - kw);
            } else src = k;
            const int ci = (cp0 + cp) * 2;
            const size_t wb = (size_t)(co_base + j) * Cin;
            wl2[t] = packh2(wt[(wb + ci) * 27 + src], wt[(wb + ci + 1) * 27 + src]);
        }
        __syncthreads();

        for (int cp = 0; cp < cnp; ++cp) {
            const f16* cb = in + (size_t)(cp0 + cp) * DD * HWin * 2;
            const unsigned* wc = wl2 + cp * 27 * CO_BLK;
#pragma unroll
            for (int kd = 0; kd < 3; ++kd) {
                const int di = d0 + kd - 1;
                if (di < 0 || di >= DD) continue;
#pragma unroll
                for (int kh = 0; kh < 3; ++kh) {
                    const int hi = h0 * STRIDE + kh - 1;
                    if (hi < 0 || hi >= Hin) continue;
                    const unsigned* rowu = (const unsigned*)
                        (cb + ((size_t)di * HWin + (size_t)hi * Win) * 2);
                    unsigned v2[10];
                    v2[0] = (w0 > 0) ? rowu[w0 - 1] : 0u;
                    const uint4 q1 = *(const uint4*)(rowu + w0);
                    const uint4 q2 = *(const uint4*)(rowu + w0 + 4);
                    v2[1] = q1.x; v2[2] = q1.y; v2[3] = q1.z; v2[4] = q1.w;
                    v2[5] = q2.x; v2[6] = q2.y; v2[7] = q2.z; v2[8] = q2.w;
                    v2[9] = (w0 + 8 < Win) ? rowu[w0 + 8] : 0u;
                    const unsigned* wk = wc + (kd * 9 + kh * 3) * CO_BLK;
#pragma unroll
                    for (int kw = 0; kw < 3; ++kw) {
#pragma unroll
                        for (int j = 0; j < CO_BLK; ++j) {
                            const unsigned wv = wk[kw * CO_BLK + j];
#pragma unroll
                            for (int o = 0; o < 8; ++o)
                                acc[j][o] = dot2f(v2[o + kw], wv, acc[j][o]);
                        }
                    }
                }
            }
        }
    }
#pragma unroll
    for (int j = 0; j < CO_BLK; ++j) {
        f16* op = out + (((size_t)(co_base + j) * DD + d0) * Hout + h0) * Wout + w0;
        unsigned dw[4];
#pragma unroll
        for (int o = 0; o < 4; ++o)
            dw[o] = packh2(acc[j][2 * o], acc[j][2 * o + 1]);
        *(uint4*)op = make_uint4(dw[0], dw[1], dw[2], dw[3]);
    }
}

// ---------------------------------------------------------------------------
// fe conv: Cin=1, fp32 input x. grid.y in {0,1,2} = z/f1/f2 group (co base
// coBase+16*y), 4 channels each, outputs 4U apart (interleaved).
// ---------------------------------------------------------------------------
__global__ __launch_bounds__(256)
void conv_fe_k(const float* __restrict__ in, const float* __restrict__ wt,
               const float* __restrict__ bias, int coBase, f16* __restrict__ out)
{
    const int cg = coBase + 16 * blockIdx.y;
    __shared__ float wl[27 * 4];
    for (int t = threadIdx.x; t < 27 * 4; t += 256)
        wl[t] = wt[(size_t)(cg + (t % 4)) * 27 + (t / 4)];
    __syncthreads();

    const int W = 256, H = 256;
    const int s8 = (blockIdx.x * 256 + threadIdx.x) * 8;
    const int w0 = s8 % W;
    const int sh = s8 / W;
    const int h0 = sh % H;
    const int d0 = sh / H;

    float acc[4][8];
#pragma unroll
    for (int j = 0; j < 4; ++j) {
        const float bvv = bias[cg + j];
#pragma unroll
        for (int o = 0; o < 8; ++o) acc[j][o] = bvv;
    }
    const size_t HW = 65536;
#pragma unroll
    for (int kd = 0; kd < 3; ++kd) {
        const int di = d0 + kd - 1;
        if (di < 0 || di >= DD) continue;
#pragma unroll
        for (int kh = 0; kh < 3; ++kh) {
            const int hi = h0 + kh - 1;
            if (hi < 0 || hi >= H) continue;
            const float* row = in + (size_t)di * HW + (size_t)hi * W + w0;
            float v[10];
            v[0] = (w0 > 0) ? row[-1] : 0.f;
            const float4 q1 = *(const float4*)row;
            const float4 q2 = *(const float4*)(row + 4);
            v[1] = q1.x; v[2] = q1.y; v[3] = q1.z; v[4] = q1.w;
            v[5] = q2.x; v[6] = q2.y; v[7] = q2.z; v[8] = q2.w;
            v[9] = (w0 + 8 < W) ? row[8] : 0.f;
            const float* wk = wl + (kd * 9 + kh * 3) * 4;
#pragma unroll
            for (int kw = 0; kw < 3; ++kw) {
#pragma unroll
                for (int j = 0; j < 4; ++j) {
                    const float wv = wk[kw * 4 + j];
#pragma unroll
                    for (int o = 0; o < 8; ++o)
                        acc[j][o] = fmaf(v[o + kw], wv, acc[j][o]);
                }
            }
        }
    }
    f16* ob = out + (size_t)blockIdx.y * 4 * U;
#pragma unroll
    for (int pj = 0; pj < 2; ++pj) {
        f16* op = ob + (((size_t)pj * DD + d0) * H + h0) * (size_t)W * 2 + (size_t)w0 * 2;
        unsigned dw[8];
#pragma unroll
        for (int o = 0; o < 8; ++o)
            dw[o] = packh2(acc[2 * pj][o], acc[2 * pj + 1][o]);
        *(uint4*)op = make_uint4(dw[0], dw[1], dw[2], dw[3]);
        *(uint4*)(op + 8) = make_uint4(dw[4], dw[5], dw[6], dw[7]);
    }
}

// ---------------------------------------------------------------------------
// fo_pool over D=31. IL: pair-interleaved [C/2][D][HW][2]; else plain.
// out may alias a1 (in-place residual: same off read-then-write per thread).
// ---------------------------------------------------------------------------
template<bool IL, typename TA1, typename TA2, typename TO>
__global__ __launch_bounds__(256)
void fo_pool_k(const f16* __restrict__ z, const f16* __restrict__ f,
               TO* out, const TA1* a1, const TA2* __restrict__ a2,
               int C, int HW, int reverse)
{
    const long long idx = (long long)blockIdx.x * 256 + threadIdx.x;
    if (idx >= (long long)C * HW) return;
    size_t base, step;
    if (IL) {
        const long long pairIdx = idx / (2LL * HW);
        const int rem = (int)(idx - pairIdx * 2LL * HW);
        base = ((size_t)pairIdx * DD * HW + (rem >> 1)) * 2 + (rem & 1);
        step = (size_t)HW * 2;
    } else {
        const int c = (int)(idx / HW);
        base = (size_t)c * DD * HW + (int)(idx - (long long)c * HW);
        step = (size_t)HW;
    }
    float h = 0.f;
    if (!reverse) {
        for (int d = 0; d < DD; ++d) {
            const size_t off = base + (size_t)d * step;
            const float zz = tanhf(toF(z[off]));
            const float ff = sigm(toF(f[off]));
            h = ff * h + (1.f - ff) * zz;
            float v = h;
            if (a1) v += toF(a1[off]);
            if (a2) v += toF(a2[off]);
            stv(out + off, v);
        }
    } else {
        for (int d = DD - 1; d >= 0; --d) {
            const size_t off = base + (size_t)d * step;
            const float zz = tanhf(toF(z[off]));
            const float ff = sigm(toF(f[off]));
            h = ff * h + (1.f - ff) * zz;
            float v = h;
            if (a1) v += toF(a1[off]);
            if (a2) v += toF(a2[off]);
            stv(out + off, v);
        }
    }
}

__global__ __launch_bounds__(256)
void diag_k(float* out, float v, int n)
{
    const int i = blockIdx.x * 256 + threadIdx.x;
    if (i < n) out[i] = v;
}

// ---------------------------------------------------------------------------

static inline void conv_mfma_launch(const f16* in, const float* w, const float* b,
                                    f16* out, int Cin, int co0, int nCo, int CoTot,
                                    int Hin, int Win, int Hout, int Wout,
                                    int stride, bool flip, hipStream_t s)
{
    const unsigned gx = (unsigned)((long long)DD * Hout * (Wout / 64));
    const float* wp = w + (size_t)co0 * Cin * 27;
    const float* bp = b + co0;
    const int CoRem = CoTot - co0;
    const int gy = (nCo + 15) / 16;
    const int nStore = (nCo % 16 == 0) ? 16 : nCo;
    dim3 g(gx, gy);
    if (stride == 2)
        conv_mfma_k<2, false, false><<<g, 256, 0, s>>>(in, nullptr, wp, bp, out,
            Cin, CoRem, nStore, Hin, Win, Hout, Wout);
    else if (flip)
        conv_mfma_k<1, true, false><<<g, 256, 0, s>>>(in, nullptr, wp, bp, out,
            Cin, CoRem, nStore, Hin, Win, Hout, Wout);
    else
        conv_mfma_k<1, false, false><<<g, 256, 0, s>>>(in, nullptr, wp, bp, out,
            Cin, CoRem, nStore, Hin, Win, Hout, Wout);
}

static inline void conv_up_mfma_launch(const f16* ia, const f16* ib,
                                       const float* w, const float* b, f16* out,
                                       int Cin, int co0, int nCo, int CoTot,
                                       int Hlo, int Wlo, hipStream_t s)
{
    const unsigned gx = (unsigned)((long long)DD * (2 * Hlo) * ((2 * Wlo) / 64));
    const float* wp = w + (size_t)co0 * Cin * 27;
    const float* bp = b + co0;
    const int CoRem = CoTot - co0;
    const int gy = (nCo + 15) / 16;
    const int nStore = (nCo % 16 == 0) ? 16 : nCo;
    dim3 g(gx, gy);
    conv_mfma_k<1, false, true><<<g, 256, 0, s>>>(ia, ib, wp, bp, out,
        Cin, CoRem, nStore, Hlo, Wlo, 2 * Hlo, 2 * Wlo);
}

template<bool IL, typename TA1, typename TA2, typename TO>
static inline void pool_launch(const f16* z, const f16* f, TO* o, const TA1* a1,
                               const TA2* a2, int C, int HW, int rev, hipStream_t s)
{
    const long long tot = (long long)C * HW;
    fo_pool_k<IL, TA1, TA2, TO><<<(unsigned)((tot + 255) / 256), 256, 0, s>>>(
        z, f, o, a1, a2, C, HW, rev);
}

// ---------------------------------------------------------------------------
// Memory plan (units of U, f16). Pool = 56U. d3/d4 use in-place residual
// pools (out aliases a1) to free 16U for 8-co gate chunks.
// ---------------------------------------------------------------------------
static void run_net(const float* x, const float* const* W, const float* const* B,
                    float* out, f16* P, hipStream_t s)
{
    const f16* np = nullptr;
    const float* npf = nullptr;

    fill_k<<<2048, 256, 0, s>>>(P, POOL_UNITS * U);

    // ---- fe pass helper: gates z/f1/f2/tmp in G[0,16U) ----
    auto fe_pass = [&](f16* FEout, f16* G) {
        for (int a = 0; a < 16; a += 4) {
            conv_fe_k<<<dim3(992, 3), 256, 0, s>>>(x, W[0], B[0], a, G);
            pool_launch<true, f16, float, f16>(G, G + 4 * U, G + 12 * U, np, npf, 4, 65536, 0, s);
            pool_launch<true, f16, float, f16>(G, G + 8 * U, FEout + (size_t)a * U,
                                               G + 12 * U, npf, 4, 65536, 1, s);
        }
    };

    f16* FE = P + 32 * U;
    fe_pass(FE, P);  // gates [0,16)

    // ---- e0 = qrnn(conv(fe), fwd) : 16 -> 32 -> 16 @256, 8-co chunks -------
    f16* E0 = P + 16 * U;
    for (int a = 0; a < 16; a += 8) {
        conv_mfma_launch(FE, W[1], B[1], P,         16, a,      8, 32, 256, 256, 256, 256, 1, false, s);
        conv_mfma_launch(FE, W[1], B[1], P + 8 * U, 16, 16 + a, 8, 32, 256, 256, 256, 256, 1, false, s);
        pool_launch<true, f16, float, f16>(P, P + 8 * U, E0 + (size_t)a * U, np, npf, 8, 65536, 0, s);
    }

    // ---- e1 = qrnn(conv(e0, s2), rev) : 16 -> 64 -> 32 @128 ----------------
    f16* E1 = P;
    {
        f16* G = P + 32 * U;
        conv_mfma_launch(E0, W[2], B[2], G, 16, 0, 64, 64, 256, 256, 128, 128, 2, false, s);
        pool_launch<true, f16, float, f16>(G, G + 8 * U, E1, np, npf, 32, 16384, 1, s);
    }

    // ---- e2 = qrnn(conv(e1), fwd) : 32 -> 64 -> 32 @128 --------------------
    f16* E2 = P + 8 * U;
    {
        f16* G = P + 32 * U;
        conv_mfma_launch(E1, W[3], B[3], G, 32, 0, 64, 64, 128, 128, 128, 128, 1, false, s);
        pool_launch<true, f16, float, f16>(G, G + 8 * U, E2, np, npf, 32, 16384, 0, s);
    }

    // ---- e3 = qrnn(conv(e2, s2), rev) : 32 -> 128 -> 64 @64 ----------------
    f16* E3 = P + 32 * U;
    {
        f16* G = P + 48 * U;
        conv_mfma_launch(E2, W[4], B[4], G, 32, 0, 128, 128, 128, 128, 64, 64, 2, false, s);
        pool_launch<true, f16, float, f16>(G, G + 4 * U, E3, np, npf, 64, 4096, 1, s);
    }

    // ---- e4 = qrnn(conv(e3), fwd) : 64 -> 128 -> 64 @64 --------------------
    f16* E4 = P + 40 * U;
    {
        f16* G = P + 48 * U;
        conv_mfma_launch(E3, W[5], B[5], G, 64, 0, 128, 128, 64, 64, 64, 64, 1, false, s);
        pool_launch<true, f16, float, f16>(G, G + 4 * U, E4, np, npf, 64, 4096, 0, s);
    }

    // ---- d0 = qrnn(deconv(e4), rev) : 64 -> 128 -> 64 @64 ------------------
    f16* D0 = P + 44 * U;
    {
        f16* G = P + 48 * U;
        conv_mfma_launch(E4, W[6], B[6], G, 64, 0, 128, 128, 64, 64, 64, 64, 1, true, s);
        pool_launch<true, f16, float, f16>(G, G + 4 * U, D0, np, npf, 64, 4096, 1, s);
    }

    // ---- d1 = qrnn(conv(up(d0+e3)), fwd) + e2 : 64 -> 64 -> 32 @128 --------
    f16* D1 = P + 36 * U;
    for (int a = 0; a < 32; a += 16) {
        f16* G = P + 48 * U;
        conv_up_mfma_launch(D0, E3, W[7], B[7], G,         64, a,      16, 64, 64, 64, s);
        conv_up_mfma_launch(D0, E3, W[7], B[7], G + 4 * U, 64, 32 + a, 16, 64, 64, 64, s);
        pool_launch<true, f16, float, f16>(G, G + 4 * U, D1 + (size_t)a * V2,
                                           E2 + (size_t)a * V2, npf, 16, 16384, 0, s);
    }

    // ---- d2 = qrnn(deconv(d1), rev) : 32 -> 64 -> 32 @128 ------------------
    f16* D2 = P + 8 * U;
    for (int a = 0; a < 32; a += 16) {
        f16* G = P + 48 * U;
        conv_mfma_launch(D1, W[8], B[8], G,         32, a,      16, 64, 128, 128, 128, 128, 1, true, s);
        conv_mfma_launch(D1, W[8], B[8], G + 4 * U, 32, 32 + a, 16, 64, 128, 128, 128, 128, 1, true, s);
        pool_launch<true, f16, float, f16>(G, G + 4 * U, D2 + (size_t)a * V2, np, npf, 16, 16384, 1, s);
    }

    // ---- d3 = qrnn(conv(up(d2+e1)), fwd) + e0 : 32 -> 32 -> 16 @256 --------
    // in-place over E0; gates 8-co chunks in [32,48)
    for (int a = 0; a < 16; a += 8) {
        f16* G = P + 32 * U;
        conv_up_mfma_launch(D2, E1, W[9], B[9], G,         32, a,      8, 32, 128, 128, s);
        conv_up_mfma_launch(D2, E1, W[9], B[9], G + 8 * U, 32, 16 + a, 8, 32, 128, 128, s);
        pool_launch<true, f16, float, f16>(G, G + 8 * U, E0 + (size_t)a * U,
                                           E0 + (size_t)a * U, npf, 8, 65536, 0, s);
    }
    f16* D3 = E0;  // [16,32)

    // ---- recompute fe -> FE2 = [0,16), gates [32,48) -----------------------
    f16* FE2 = P;
    fe_pass(FE2, P + 32 * U);

    // ---- d4 = qrnn(deconv(d3), rev) + fe : 16 -> 32 -> 16 @256 -------------
    // in-place over FE2; gates 8-co chunks in [32,48)
    for (int a = 0; a < 16; a += 8) {
        f16* G = P + 32 * U;
        conv_mfma_launch(D3, W[10], B[10], G,         16, a,      8, 32, 256, 256, 256, 256, 1, true, s);
        conv_mfma_launch(D3, W[10], B[10], G + 8 * U, 16, 16 + a, 8, 32, 256, 256, 256, 256, 1, true, s);
        pool_launch<true, f16, float, f16>(G, G + 8 * U, FE2 + (size_t)a * U,
                                           FE2 + (size_t)a * U, npf, 8, 65536, 1, s);
    }
    f16* D4 = FE2;  // [0,16)

    // ---- out = biqrnn(deconv(d4)) + x : 16 -> 3 -> 1 @256 -> fp32 d_out ----
    {
        f16* G = P + 16 * U;       // plain: ch0 z, ch1 f1, ch2 f2
        f16* TMP = P + 19 * U;
        dim3 g(992, 1);
        conv3d_il_k<1, true, 3, false><<<g, 256, (size_t)8 * 27 * 3 * 4, s>>>(
            D4, W[11], B[11], G, 16, 256, 256, 256, 256);
        pool_launch<false, f16, float, f16>(G, G + 1 * U, TMP, np, npf, 1, 65536, 0, s);
        pool_launch<false, f16, float, float>(G, G + 2 * U, out, TMP, x, 1, 65536, 1, s);
    }
}

extern "C" void kernel_launch(void* const* d_in, const int* in_sizes, int n_in,
                              void* d_out, int out_size, void* d_ws, size_t ws_size,
                              hipStream_t stream)
{
    const float* x = (const float*)d_in[0];
    const float* W[12];
    const float* B[12];
    for (int i = 0; i < 12; ++i) {
        W[i] = (const float*)d_in[1 + 2 * i];
        B[i] = (const float*)d_in[2 + 2 * i];
    }

    const size_t need = (size_t)(POOL_UNITS * U) * sizeof(f16);  // ~227 MB
    if (ws_size >= need) {
        run_net(x, W, B, (float*)d_out, (f16*)d_ws, stream);
    } else {
        const float ws_mb = (float)((double)ws_size / 1048576.0);
        diag_k<<<(out_size + 255) / 256, 256, 0, stream>>>(
            (float*)d_out, ws_mb, out_size);
    }
}